// Round 4
// baseline (1106.256 us; speedup 1.0000x reference)
//
#include <hip/hip_runtime.h>
#include <cstdint>
#include <cstddef>

// CriticGNN: GENConv(softmax aggr) + MLP/BN + mean-pool + head. All fp32.
// R7 profile: k_scatter_idx@4edges/thread = 286us (WORSE than perm's 206):
// 8 VGPRs -> the 4 atomic->dependent-store chains serialized per thread with
// 4x fewer threads to hide ~500cy atomic latency. Gather<false> confirmed
// fine (absent from top-5; L3 absorbs random ea reads).
// R8: scatter back to 1 edge/thread (perm's issue structure, 1 random
// line-touch/edge instead of perm's 2). Everything else unchanged from R7.

#define N_NODES 100000
#define N_EDGES 3200000
#define B_GRAPHS 64
#define F_INF 64
#define E_INF 16
#define A_DIM 13
#define H_DIM 32
#define O_DIM 64
#define EPS_GEN 1e-7f
#define EPS_BN 1e-5f
#define SCAN_BLOCKS 391

// ---- K1: node encoder h = x @ node_w + node_b  [N,64]x[64,32] -> [N,32]
__global__ __launch_bounds__(256) void k_node_enc(
        const float* __restrict__ x, const float* __restrict__ w,
        const float* __restrict__ b, float* __restrict__ h) {
    __shared__ float sW[F_INF * H_DIM];
    __shared__ float sB[H_DIM];
    __shared__ float sX[8 * F_INF];
    int tid = threadIdx.x;
    for (int i = tid; i < F_INF * H_DIM; i += 256) sW[i] = w[i];
    if (tid < H_DIM) sB[tid] = b[tid];
    int node0 = blockIdx.x * 8;
    const float2* xp = (const float2*)(x + (size_t)node0 * F_INF);
    float2 v = xp[tid];
    sX[2 * tid] = v.x;
    sX[2 * tid + 1] = v.y;
    __syncthreads();
    int nl = tid >> 5, ch = tid & 31;
    float acc = sB[ch];
    const float* xr = &sX[nl * F_INF];
#pragma unroll
    for (int k = 0; k < F_INF; k++) acc = fmaf(xr[k], sW[k * H_DIM + ch], acc);
    h[(size_t)(node0 + nl) * H_DIM + ch] = acc;
}

// ---- K2a: histogram of dst degrees (int4-vectorized reads)
__global__ __launch_bounds__(256) void k_hist(
        const int* __restrict__ ei, int* __restrict__ deg) {
    int i = blockIdx.x * 256 + threadIdx.x;
    if (i >= N_EDGES / 4) return;
    int4 d = ((const int4*)(ei + N_EDGES))[i];
    atomicAdd(&deg[d.x], 1);
    atomicAdd(&deg[d.y], 1);
    atomicAdd(&deg[d.z], 1);
    atomicAdd(&deg[d.w], 1);
}

// ---- K2b: per-256-block inclusive scan of deg -> incl, block sums -> bsum
__global__ __launch_bounds__(256) void k_scan1(
        const int* __restrict__ deg, int* __restrict__ incl,
        int* __restrict__ bsum) {
    __shared__ int s[256];
    int tid = threadIdx.x;
    int i = blockIdx.x * 256 + tid;
    int v = (i < N_NODES) ? deg[i] : 0;
    s[tid] = v;
    __syncthreads();
    for (int d = 1; d < 256; d <<= 1) {
        int t = (tid >= d) ? s[tid - d] : 0;
        __syncthreads();
        s[tid] += t;
        __syncthreads();
    }
    if (i < N_NODES) incl[i] = s[tid];
    if (tid == 255) bsum[blockIdx.x] = s[255];
}

// ---- K2c: scan block sums in-place -> exclusive
__global__ __launch_bounds__(512) void k_scan2(int* __restrict__ bsum) {
    __shared__ int s[512];
    int t = threadIdx.x;
    int v = (t < SCAN_BLOCKS) ? bsum[t] : 0;
    s[t] = v;
    __syncthreads();
    for (int d = 1; d < 512; d <<= 1) {
        int tv = (t >= d) ? s[t - d] : 0;
        __syncthreads();
        s[t] += tv;
        __syncthreads();
    }
    if (t < SCAN_BLOCKS) bsum[t] = s[t] - v;  // exclusive
}

// ---- K2d: finalize offsets (into deg array) + cursor copy (into incl array)
__global__ __launch_bounds__(256) void k_scan3(
        int* __restrict__ deg_offs, int* __restrict__ incl_cursor,
        const int* __restrict__ bsum) {
    int i = blockIdx.x * 256 + threadIdx.x;
    if (i >= N_NODES) return;
    int o = bsum[i >> 8] + incl_cursor[i] - deg_offs[i];  // exclusive prefix
    deg_offs[i] = o;
    incl_cursor[i] = o;
    if (i == 0) deg_offs[N_NODES] = N_EDGES;
}

// ---- K2e: scatter edge records (indexed-gather path), 1 edge/thread.
// One short atomic->store chain per thread, max TLP to hide atomic latency.
__global__ __launch_bounds__(256) void k_scatter_idx(
        const int* __restrict__ ei, int* __restrict__ cursor,
        uint2* __restrict__ sorted) {
    int e = blockIdx.x * 256 + threadIdx.x;
    if (e >= N_EDGES) return;
    int src = ei[e];
    int d = ei[N_EDGES + e];
    int pos = atomicAdd(&cursor[d], 1);
    sorted[pos] = make_uint2((unsigned)e, (unsigned)src);
}

// ---- K3: atomic-free gather + softmax-aggregate + root-add.
// One wave per node; half-wave (32 lanes = 32 channels) per edge.
// 16-edge chunks, per-wave-private double-buffered LDS for ea rows:
//   stage chunk c+16 (1 coop wave load -> regs, ds_write after compute)
//   hs (h[src]) loads for chunk c+16 issued before computing chunk c
//   weight column in 16 VGPRs per lane; no barriers anywhere.
template <bool PERM>
__global__ __launch_bounds__(256, 4) void k_gather(
        const float* __restrict__ easrc, const int* __restrict__ srcp,
        const uint2* __restrict__ sorted, const int* __restrict__ offs,
        const float* __restrict__ ew, const float* __restrict__ eb,
        const float* __restrict__ h, float* __restrict__ conv) {
    __shared__ float sEA[4 * 2 * 256];   // 4 waves x 2 bufs x (16 edges x 16 f)
    int tid = threadIdx.x;
    int wave = tid >> 6, lane = tid & 63;
    int p = lane >> 5;     // half-wave id
    int j = lane & 31;     // channel
    int v = blockIdx.x * 4 + wave;       // grid 25000 -> exact cover
    int s0 = offs[v], s1 = offs[v + 1];
    float wj[16];
#pragma unroll
    for (int k = 0; k < 16; k++) wj[k] = ew[k * H_DIM + j];
    float bj = eb[j];
    float hv = h[(size_t)v * H_DIM + j];
    float se = 0.0f, sme = 0.0f;
    float* myEA = &sEA[wave * 512];

    if (s0 < s1) {
        const int s1m1 = s1 - 1;
        const int w16 = lane & 15;   // edge slot for src-chunk load
        const int row4 = lane >> 2;  // edge slot for ea staging (0..15)
        const int part = lane & 3;   // float4 part within ea row
        float hs_cur[8], hs_next[8];
        float4 st;
        uint2 srtN = make_uint2(0u, 0u);  // idx path: next-chunk (eid,src)
        unsigned scN = 0;                 // perm path: next-chunk src
        int c = s0, buf = 0;
        // ---- prologue: chunk0
        {
            unsigned sc0;
            if constexpr (PERM) {
                sc0 = (unsigned)srcp[min(c + w16, s1m1)];
                st = ((const float4*)easrc)[(size_t)min(c + row4, s1m1) * 4 + part];
            } else {
                uint2 srt0 = sorted[min(c + w16, s1m1)];
                sc0 = srt0.y;
                unsigned eid = (unsigned)__shfl((int)srt0.x, row4);
                st = ((const float4*)easrc)[(size_t)eid * 4 + part];
            }
#pragma unroll
            for (int t = 0; t < 8; t++) {
                int sc = __shfl((int)sc0, 2 * t + p);
                hs_cur[t] = h[(size_t)sc * H_DIM + j];
            }
            if constexpr (PERM) scN = (unsigned)srcp[min(c + 16 + w16, s1m1)];
            else srtN = sorted[min(c + 16 + w16, s1m1)];
            ((float4*)myEA)[lane] = st;   // buf0
        }
        for (;;) {
            bool more = (c + 16 < s1);
            if (more) {
                // stage chunk c+16 into regs; issue its hs loads; prefetch c+32 srcs
                if constexpr (PERM) {
                    st = ((const float4*)easrc)[(size_t)min(c + 16 + row4, s1m1) * 4 + part];
                } else {
                    unsigned eid = (unsigned)__shfl((int)srtN.x, row4);
                    st = ((const float4*)easrc)[(size_t)eid * 4 + part];
                }
                unsigned scsrc = PERM ? scN : srtN.y;
#pragma unroll
                for (int t = 0; t < 8; t++) {
                    int sc = __shfl((int)scsrc, 2 * t + p);
                    hs_next[t] = h[(size_t)sc * H_DIM + j];
                }
                if constexpr (PERM) scN = (unsigned)srcp[min(c + 32 + w16, s1m1)];
                else srtN = sorted[min(c + 32 + w16, s1m1)];
            }
            // compute chunk c from LDS[buf] + hs_cur
            const float* cb = &myEA[buf * 256];
#pragma unroll
            for (int t = 0; t < 8; t++) {
                int e = 2 * t + p;
                if (c + e < s1) {
                    const float4* er = (const float4*)&cb[e * 16];
                    float4 q0 = er[0], q1 = er[1], q2 = er[2], q3 = er[3];
                    float acc = bj;
                    acc = fmaf(q0.x, wj[0], acc);
                    acc = fmaf(q0.y, wj[1], acc);
                    acc = fmaf(q0.z, wj[2], acc);
                    acc = fmaf(q0.w, wj[3], acc);
                    acc = fmaf(q1.x, wj[4], acc);
                    acc = fmaf(q1.y, wj[5], acc);
                    acc = fmaf(q1.z, wj[6], acc);
                    acc = fmaf(q1.w, wj[7], acc);
                    acc = fmaf(q2.x, wj[8], acc);
                    acc = fmaf(q2.y, wj[9], acc);
                    acc = fmaf(q2.z, wj[10], acc);
                    acc = fmaf(q2.w, wj[11], acc);
                    acc = fmaf(q3.x, wj[12], acc);
                    acc = fmaf(q3.y, wj[13], acc);
                    acc = fmaf(q3.z, wj[14], acc);
                    acc = fmaf(q3.w, wj[15], acc);
                    float m = fmaxf(acc + hs_cur[t], 0.0f) + EPS_GEN;
                    float ex = __expf(m);
                    se += ex;
                    sme += m * ex;
                }
            }
            if (!more) break;
            ((float4*)(myEA + (buf ^ 1) * 256))[lane] = st;
#pragma unroll
            for (int t = 0; t < 8; t++) hs_cur[t] = hs_next[t];
            c += 16;
            buf ^= 1;
        }
    }
    se += __shfl_xor(se, 32);
    sme += __shfl_xor(sme, 32);
    if (p == 0) {
        float r = (se > 0.0f) ? (sme / se) : 0.0f;
        conv[(size_t)v * H_DIM + j] = r + hv;
    }
}

// ---- K4: fused Lin (+optional folded-BN+ReLU on input) (+optional BN-stats)
// 16 nodes per stage iteration: 2 syncs per 1024 FMA/thread-block-iter.
template <int IN_CH, bool BN_IN, bool STATS>
__global__ __launch_bounds__(256) void k_lin(
        const float* __restrict__ in, const float* __restrict__ w,
        const float* __restrict__ b, const float* __restrict__ ss,
        float* __restrict__ out, float* __restrict__ stats) {
    __shared__ float sW[IN_CH * O_DIM];
    __shared__ float sB[O_DIM];
    __shared__ float sS[IN_CH], sH[IN_CH];
    __shared__ float sX[16 * IN_CH];
    __shared__ float r1[256], r2[256];
    int tid = threadIdx.x;
    for (int i = tid; i < IN_CH * O_DIM; i += 256) sW[i] = w[i];
    if (tid < O_DIM) sB[tid] = b[tid];
    if constexpr (BN_IN) {
        if (tid < IN_CH) { sS[tid] = ss[tid]; sH[tid] = ss[64 + tid]; }
    }
    int ch = tid & 63, nl = tid >> 6;
    float s1 = 0.0f, s2 = 0.0f;
    const int ngroups = N_NODES / 16;  // 6250
    __syncthreads();
    for (int g = blockIdx.x; g < ngroups; g += gridDim.x) {
        size_t base = (size_t)g * 16 * IN_CH;
        __syncthreads();
        if constexpr (IN_CH == 64) {
            float4 v = ((const float4*)(in + base))[tid];
            if constexpr (BN_IN) {
                int c0 = (tid * 4) & 63;
                v.x = fmaxf(fmaf(v.x, sS[c0], sH[c0]), 0.0f);
                v.y = fmaxf(fmaf(v.y, sS[c0 + 1], sH[c0 + 1]), 0.0f);
                v.z = fmaxf(fmaf(v.z, sS[c0 + 2], sH[c0 + 2]), 0.0f);
                v.w = fmaxf(fmaf(v.w, sS[c0 + 3], sH[c0 + 3]), 0.0f);
            }
            ((float4*)sX)[tid] = v;
        } else {
            float2 v = ((const float2*)(in + base))[tid];
            if constexpr (BN_IN) {
                int c0 = (tid * 2) & (IN_CH - 1);
                v.x = fmaxf(fmaf(v.x, sS[c0], sH[c0]), 0.0f);
                v.y = fmaxf(fmaf(v.y, sS[c0 + 1], sH[c0 + 1]), 0.0f);
            }
            ((float2*)sX)[tid] = v;
        }
        __syncthreads();
#pragma unroll
        for (int q = 0; q < 4; q++) {
            const float* xr = &sX[(nl + 4 * q) * IN_CH];
            float acc = sB[ch];
#pragma unroll
            for (int k = 0; k < IN_CH; k++) acc = fmaf(xr[k], sW[k * O_DIM + ch], acc);
            out[(size_t)(g * 16 + nl + 4 * q) * O_DIM + ch] = acc;
            if constexpr (STATS) { s1 += acc; s2 += acc * acc; }
        }
    }
    if constexpr (STATS) {
        __syncthreads();
        r1[tid] = s1; r2[tid] = s2;
        __syncthreads();
        if (tid < 64) {
            float a1 = r1[tid] + r1[tid + 64] + r1[tid + 128] + r1[tid + 192];
            float a2 = r2[tid] + r2[tid + 64] + r2[tid + 128] + r2[tid + 192];
            unsafeAtomicAdd(&stats[tid], a1);
            unsafeAtomicAdd(&stats[64 + tid], a2);
        }
    }
}

// ---- K5: finalize BN stats -> folded scale/shift
__global__ void k_bnfin(const float* __restrict__ stats, const float* __restrict__ g,
                        const float* __restrict__ b, float* __restrict__ ss) {
    int c = threadIdx.x;
    if (c >= 64) return;
    const float invN = 1.0f / (float)N_NODES;
    float mu = stats[c] * invN;
    float var = fmaxf(stats[64 + c] * invN - mu * mu, 0.0f);
    float rs = 1.0f / sqrtf(var + EPS_BN);
    float sc = g[c] * rs;
    ss[c] = sc;
    ss[64 + c] = b[c] - mu * sc;
}

// ---- K6: graph boundaries via binary search over sorted batch
__global__ void k_bounds(const int* __restrict__ batch, int* __restrict__ start) {
    int g = threadIdx.x;
    if (g > B_GRAPHS) return;
    int lo = 0, hi = N_NODES;
    while (lo < hi) {
        int mid = (lo + hi) >> 1;
        if (batch[mid] < g) lo = mid + 1; else hi = mid;
    }
    start[g] = lo;
}

// ---- K7: segmented mean-pool partials (4 blocks per graph)
__global__ __launch_bounds__(256) void k_pool(
        const float* __restrict__ no, const int* __restrict__ start,
        float* __restrict__ gsum) {
    int g = blockIdx.x >> 2, q = blockIdx.x & 3;
    int s0 = start[g], s1e = start[g + 1];
    int len = s1e - s0;
    int per = (len + 3) >> 2;
    int a = s0 + q * per;
    int bnd = min(s0 + (q + 1) * per, s1e);
    int ch = threadIdx.x & 63, nl = threadIdx.x >> 6;
    float acc = 0.0f;
    for (int n = a + nl; n < bnd; n += 4) acc += no[(size_t)n * O_DIM + ch];
    __shared__ float r[256];
    r[threadIdx.x] = acc;
    __syncthreads();
    if (threadIdx.x < 64) {
        float v = r[ch] + r[ch + 64] + r[ch + 128] + r[ch + 192];
        unsafeAtomicAdd(&gsum[g * O_DIM + ch], v);
    }
}

// ---- K8: head (one thread per graph)
__global__ void k_head(const float* __restrict__ gsum, const int* __restrict__ start,
                       const float* __restrict__ action,
                       const float* __restrict__ pinw, const float* __restrict__ pinb,
                       const float* __restrict__ phw, const float* __restrict__ phb,
                       const float* __restrict__ pow_, const float* __restrict__ pob,
                       float* __restrict__ outp) {
    int g = threadIdx.x;
    if (g >= B_GRAPHS) return;
    int cnt = start[g + 1] - start[g];
    float inv = 1.0f / (float)max(cnt, 1);
    float mol[64];
#pragma unroll
    for (int c = 0; c < 64; c++) mol[c] = gsum[g * 64 + c] * inv;
    float fp[16];
#pragma unroll
    for (int j = 0; j < 16; j++) {
        float a = pinb[j];
        for (int c = 0; c < 64; c++) a = fmaf(mol[c], pinw[c * 16 + j], a);
        fp[j] = fmaxf(a, 0.0f);
    }
    float pol[10];
#pragma unroll
    for (int j = 0; j < 10; j++) {
        float a = phb[j];
        for (int k = 0; k < 16; k++) a = fmaf(fp[k], phw[k * 10 + j], a);
        for (int k = 0; k < 13; k++) a = fmaf(action[g * 13 + k], phw[(16 + k) * 10 + j], a);
        pol[j] = fmaxf(a, 0.0f);
    }
    float o = pob[0];
#pragma unroll
    for (int j = 0; j < 10; j++) o = fmaf(pol[j], pow_[j], o);
    outp[g] = o;
}

extern "C" void kernel_launch(void* const* d_in, const int* in_sizes, int n_in,
                              void* d_out, int out_size, void* d_ws, size_t ws_size,
                              hipStream_t stream) {
    const float* x      = (const float*)d_in[0];
    const int*   ei     = (const int*)d_in[1];
    const float* ea     = (const float*)d_in[2];
    const int*   batch  = (const int*)d_in[3];
    const float* action = (const float*)d_in[4];
    const float* node_w = (const float*)d_in[5];
    const float* node_b = (const float*)d_in[6];
    const float* edge_w = (const float*)d_in[7];
    const float* edge_b = (const float*)d_in[8];
    const float* w1 = (const float*)d_in[9];   const float* b1 = (const float*)d_in[10];
    const float* g1 = (const float*)d_in[11];  const float* bb1 = (const float*)d_in[12];
    const float* w2 = (const float*)d_in[13];  const float* b2 = (const float*)d_in[14];
    const float* g2 = (const float*)d_in[15];  const float* bb2 = (const float*)d_in[16];
    const float* w3 = (const float*)d_in[17];  const float* b3 = (const float*)d_in[18];
    const float* g3 = (const float*)d_in[19];  const float* bb3 = (const float*)d_in[20];
    const float* w4 = (const float*)d_in[21];  const float* b4 = (const float*)d_in[22];
    const float* pinw = (const float*)d_in[23]; const float* pinb = (const float*)d_in[24];
    const float* phw  = (const float*)d_in[25]; const float* phb  = (const float*)d_in[26];
    const float* pow_ = (const float*)d_in[27]; const float* pob  = (const float*)d_in[28];

    // ---- common workspace prefix
    char* wsb = (char*)d_ws;
    size_t off = 0;
    float* stats  = (float*)(wsb + off); off += 512 * 4;       // zeroed
    float* gsum   = (float*)(wsb + off); off += 4096 * 4;      // zeroed
    int*   offs   = (int*)  (wsb + off); off += 400128;        // deg->offs (zeroed)
    size_t zero_bytes = off;
    int*   cursor = (int*)  (wsb + off); off += 400128;
    int*   bsum   = (int*)  (wsb + off); off += 2048;
    float* ssb    = (float*)(wsb + off); off += 512 * 4;
    int*   start  = (int*)  (wsb + off); off += 512;
    int*   srcp   = (int*)  (wsb + off); off += (size_t)N_EDGES * 4;         // 12.8MB (unused R8)
    float* h      = (float*)(wsb + off); off += (size_t)N_NODES * H_DIM * 4; // 12.8MB
    float* conv   = (float*)(wsb + off); off += (size_t)N_NODES * H_DIM * 4; // 12.8MB
    size_t tail = off;
    (void)srcp;
    // Indexed path: sorted (25.6MB) at tail; t1 overlays sorted,
    // t2 overlays h+conv (safe: P1 reads conv before P2 writes t2).
    uint2* sorted = (uint2*)(wsb + tail);
    float* t1 = (float*)sorted;            // 25.6MB overlay
    float* t2 = h;                         // 25.6MB spans h+conv

    hipMemsetAsync(d_ws, 0, zero_bytes, stream);

    k_node_enc<<<N_NODES / 8, 256, 0, stream>>>(x, node_w, node_b, h);
    // build dst-CSR
    k_hist<<<(N_EDGES / 4 + 255) / 256, 256, 0, stream>>>(ei, offs);
    k_scan1<<<SCAN_BLOCKS, 256, 0, stream>>>(offs, cursor, bsum);
    k_scan2<<<1, 512, 0, stream>>>(bsum);
    k_scan3<<<SCAN_BLOCKS, 256, 0, stream>>>(offs, cursor, bsum);
    k_scatter_idx<<<(N_EDGES + 255) / 256, 256, 0, stream>>>(ei, cursor, sorted);
    k_gather<false><<<N_NODES / 4, 256, 0, stream>>>(ea, nullptr, sorted, offs,
                                                     edge_w, edge_b, h, conv);
    // MLP: P1 32->64 (stats1), P2/P3 64->64 (bn in, stats), P4 64->64 (bn in)
    k_lin<32, false, true><<<1250, 256, 0, stream>>>(conv, w1, b1, nullptr, t1, stats + 0);
    k_bnfin<<<1, 64, 0, stream>>>(stats + 0, g1, bb1, ssb + 0);
    k_lin<64, true, true><<<1250, 256, 0, stream>>>(t1, w2, b2, ssb + 0, t2, stats + 128);
    k_bnfin<<<1, 64, 0, stream>>>(stats + 128, g2, bb2, ssb + 128);
    k_lin<64, true, true><<<1250, 256, 0, stream>>>(t2, w3, b3, ssb + 128, t1, stats + 256);
    k_bnfin<<<1, 64, 0, stream>>>(stats + 256, g3, bb3, ssb + 256);
    k_lin<64, true, false><<<1250, 256, 0, stream>>>(t1, w4, b4, ssb + 256, t2, nullptr);
    k_bounds<<<1, 128, 0, stream>>>(batch, start);
    k_pool<<<B_GRAPHS * 4, 256, 0, stream>>>(t2, start, gsum);
    k_head<<<1, 64, 0, stream>>>(gsum, start, action, pinw, pinb, phw, phb, pow_, pob,
                                 (float*)d_out);
}

// Round 5
// 1007.259 us; speedup vs baseline: 1.0983x; 1.0983x over previous
//
#include <hip/hip_runtime.h>
#include <cstdint>
#include <cstddef>

// CriticGNN: GENConv(softmax aggr) + MLP/BN + mean-pool + head. All fp32.
// R7/R8 lesson: idx scatter (8B records, 286us) is SLOWER than perm scatter
// (64B payload, 206us) despite 2.5x fewer bytes; gather is insensitive to
// perm-vs-idx (L3 absorbs random ea reads). Best known config = R6 (perm).
// R9: revert to perm path + delete 5 serial launches:
//   bnfin x3 -> folded into next k_lin prologue (redundant per-block BN fold)
//   scan2   -> folded into scan3 (per-block reduce of <=391 block sums)
//   bounds  -> folded into pool (thread0 bsearch + LDS) and head (per-thread)

#define N_NODES 100000
#define N_EDGES 3200000
#define B_GRAPHS 64
#define F_INF 64
#define E_INF 16
#define A_DIM 13
#define H_DIM 32
#define O_DIM 64
#define EPS_GEN 1e-7f
#define EPS_BN 1e-5f
#define SCAN_BLOCKS 391

// ---- K1: node encoder h = x @ node_w + node_b  [N,64]x[64,32] -> [N,32]
__global__ __launch_bounds__(256) void k_node_enc(
        const float* __restrict__ x, const float* __restrict__ w,
        const float* __restrict__ b, float* __restrict__ h) {
    __shared__ float sW[F_INF * H_DIM];
    __shared__ float sB[H_DIM];
    __shared__ float sX[8 * F_INF];
    int tid = threadIdx.x;
    for (int i = tid; i < F_INF * H_DIM; i += 256) sW[i] = w[i];
    if (tid < H_DIM) sB[tid] = b[tid];
    int node0 = blockIdx.x * 8;
    const float2* xp = (const float2*)(x + (size_t)node0 * F_INF);
    float2 v = xp[tid];
    sX[2 * tid] = v.x;
    sX[2 * tid + 1] = v.y;
    __syncthreads();
    int nl = tid >> 5, ch = tid & 31;
    float acc = sB[ch];
    const float* xr = &sX[nl * F_INF];
#pragma unroll
    for (int k = 0; k < F_INF; k++) acc = fmaf(xr[k], sW[k * H_DIM + ch], acc);
    h[(size_t)(node0 + nl) * H_DIM + ch] = acc;
}

// ---- K2a: histogram of dst degrees (int4-vectorized reads)
__global__ __launch_bounds__(256) void k_hist(
        const int* __restrict__ ei, int* __restrict__ deg) {
    int i = blockIdx.x * 256 + threadIdx.x;
    if (i >= N_EDGES / 4) return;
    int4 d = ((const int4*)(ei + N_EDGES))[i];
    atomicAdd(&deg[d.x], 1);
    atomicAdd(&deg[d.y], 1);
    atomicAdd(&deg[d.z], 1);
    atomicAdd(&deg[d.w], 1);
}

// ---- K2b: per-256-block inclusive scan of deg -> incl, block sums -> bsum
__global__ __launch_bounds__(256) void k_scan1(
        const int* __restrict__ deg, int* __restrict__ incl,
        int* __restrict__ bsum) {
    __shared__ int s[256];
    int tid = threadIdx.x;
    int i = blockIdx.x * 256 + tid;
    int v = (i < N_NODES) ? deg[i] : 0;
    s[tid] = v;
    __syncthreads();
    for (int d = 1; d < 256; d <<= 1) {
        int t = (tid >= d) ? s[tid - d] : 0;
        __syncthreads();
        s[tid] += t;
        __syncthreads();
    }
    if (i < N_NODES) incl[i] = s[tid];
    if (tid == 255) bsum[blockIdx.x] = s[255];
}

// ---- K2d: finalize offsets + cursor copy; fuses the block-sum scan (scan2).
__global__ __launch_bounds__(256) void k_scan3(
        int* __restrict__ deg_offs, int* __restrict__ incl_cursor,
        const int* __restrict__ bsum) {
    __shared__ int red[256];
    int tid = threadIdx.x;
    int b = blockIdx.x;
    // exclusive prefix of bsum over blocks < b (<=2 strided loads/thread)
    int vsum = 0;
    for (int t = tid; t < b; t += 256) vsum += bsum[t];
    red[tid] = vsum;
    __syncthreads();
    for (int s = 128; s > 0; s >>= 1) {
        if (tid < s) red[tid] += red[tid + s];
        __syncthreads();
    }
    int prefix = red[0];
    int i = b * 256 + tid;
    if (i >= N_NODES) return;
    int o = prefix + incl_cursor[i] - deg_offs[i];  // exclusive prefix
    deg_offs[i] = o;
    incl_cursor[i] = o;
    if (i == 0) deg_offs[N_NODES] = N_EDGES;
}

// ---- K2e-A: scatter with ea permutation (streaming-gather path)
__global__ __launch_bounds__(256) void k_scatter_perm(
        const int* __restrict__ ei, int* __restrict__ cursor,
        const float* __restrict__ ea, float* __restrict__ eap,
        int* __restrict__ srcp) {
    int e = blockIdx.x * 256 + threadIdx.x;
    if (e >= N_EDGES) return;
    int src = ei[e];
    int d = ei[N_EDGES + e];
    const float4* er = (const float4*)(ea + (size_t)e * E_INF);
    float4 q0 = er[0], q1 = er[1], q2 = er[2], q3 = er[3];
    int pos = atomicAdd(&cursor[d], 1);
    float4* wr = (float4*)(eap + (size_t)pos * E_INF);
    wr[0] = q0; wr[1] = q1; wr[2] = q2; wr[3] = q3;
    srcp[pos] = src;
}

// ---- K2e-B: scatter edge records only (indexed-gather fallback)
__global__ __launch_bounds__(256) void k_scatter_idx(
        const int* __restrict__ ei, int* __restrict__ cursor,
        uint2* __restrict__ sorted) {
    int e = blockIdx.x * 256 + threadIdx.x;
    if (e >= N_EDGES) return;
    int src = ei[e];
    int d = ei[N_EDGES + e];
    int pos = atomicAdd(&cursor[d], 1);
    sorted[pos] = make_uint2((unsigned)e, (unsigned)src);
}

// ---- K3: atomic-free gather + softmax-aggregate + root-add.
// One wave per node; half-wave (32 lanes = 32 channels) per edge.
// 16-edge chunks, per-wave-private double-buffered LDS for ea rows:
//   stage chunk c+16 (1 coop wave load -> regs, ds_write after compute)
//   hs (h[src]) loads for chunk c+16 issued before computing chunk c
//   weight column in 16 VGPRs per lane; no barriers anywhere.
template <bool PERM>
__global__ __launch_bounds__(256, 4) void k_gather(
        const float* __restrict__ easrc, const int* __restrict__ srcp,
        const uint2* __restrict__ sorted, const int* __restrict__ offs,
        const float* __restrict__ ew, const float* __restrict__ eb,
        const float* __restrict__ h, float* __restrict__ conv) {
    __shared__ float sEA[4 * 2 * 256];   // 4 waves x 2 bufs x (16 edges x 16 f)
    int tid = threadIdx.x;
    int wave = tid >> 6, lane = tid & 63;
    int p = lane >> 5;     // half-wave id
    int j = lane & 31;     // channel
    int v = blockIdx.x * 4 + wave;       // grid 25000 -> exact cover
    int s0 = offs[v], s1 = offs[v + 1];
    float wj[16];
#pragma unroll
    for (int k = 0; k < 16; k++) wj[k] = ew[k * H_DIM + j];
    float bj = eb[j];
    float hv = h[(size_t)v * H_DIM + j];
    float se = 0.0f, sme = 0.0f;
    float* myEA = &sEA[wave * 512];

    if (s0 < s1) {
        const int s1m1 = s1 - 1;
        const int w16 = lane & 15;   // edge slot for src-chunk load
        const int row4 = lane >> 2;  // edge slot for ea staging (0..15)
        const int part = lane & 3;   // float4 part within ea row
        float hs_cur[8], hs_next[8];
        float4 st;
        uint2 srtN = make_uint2(0u, 0u);  // idx path: next-chunk (eid,src)
        unsigned scN = 0;                 // perm path: next-chunk src
        int c = s0, buf = 0;
        // ---- prologue: chunk0
        {
            unsigned sc0;
            if constexpr (PERM) {
                sc0 = (unsigned)srcp[min(c + w16, s1m1)];
                st = ((const float4*)easrc)[(size_t)min(c + row4, s1m1) * 4 + part];
            } else {
                uint2 srt0 = sorted[min(c + w16, s1m1)];
                sc0 = srt0.y;
                unsigned eid = (unsigned)__shfl((int)srt0.x, row4);
                st = ((const float4*)easrc)[(size_t)eid * 4 + part];
            }
#pragma unroll
            for (int t = 0; t < 8; t++) {
                int sc = __shfl((int)sc0, 2 * t + p);
                hs_cur[t] = h[(size_t)sc * H_DIM + j];
            }
            if constexpr (PERM) scN = (unsigned)srcp[min(c + 16 + w16, s1m1)];
            else srtN = sorted[min(c + 16 + w16, s1m1)];
            ((float4*)myEA)[lane] = st;   // buf0
        }
        for (;;) {
            bool more = (c + 16 < s1);
            if (more) {
                // stage chunk c+16 into regs; issue its hs loads; prefetch c+32 srcs
                if constexpr (PERM) {
                    st = ((const float4*)easrc)[(size_t)min(c + 16 + row4, s1m1) * 4 + part];
                } else {
                    unsigned eid = (unsigned)__shfl((int)srtN.x, row4);
                    st = ((const float4*)easrc)[(size_t)eid * 4 + part];
                }
                unsigned scsrc = PERM ? scN : srtN.y;
#pragma unroll
                for (int t = 0; t < 8; t++) {
                    int sc = __shfl((int)scsrc, 2 * t + p);
                    hs_next[t] = h[(size_t)sc * H_DIM + j];
                }
                if constexpr (PERM) scN = (unsigned)srcp[min(c + 32 + w16, s1m1)];
                else srtN = sorted[min(c + 32 + w16, s1m1)];
            }
            // compute chunk c from LDS[buf] + hs_cur
            const float* cb = &myEA[buf * 256];
#pragma unroll
            for (int t = 0; t < 8; t++) {
                int e = 2 * t + p;
                if (c + e < s1) {
                    const float4* er = (const float4*)&cb[e * 16];
                    float4 q0 = er[0], q1 = er[1], q2 = er[2], q3 = er[3];
                    float acc = bj;
                    acc = fmaf(q0.x, wj[0], acc);
                    acc = fmaf(q0.y, wj[1], acc);
                    acc = fmaf(q0.z, wj[2], acc);
                    acc = fmaf(q0.w, wj[3], acc);
                    acc = fmaf(q1.x, wj[4], acc);
                    acc = fmaf(q1.y, wj[5], acc);
                    acc = fmaf(q1.z, wj[6], acc);
                    acc = fmaf(q1.w, wj[7], acc);
                    acc = fmaf(q2.x, wj[8], acc);
                    acc = fmaf(q2.y, wj[9], acc);
                    acc = fmaf(q2.z, wj[10], acc);
                    acc = fmaf(q2.w, wj[11], acc);
                    acc = fmaf(q3.x, wj[12], acc);
                    acc = fmaf(q3.y, wj[13], acc);
                    acc = fmaf(q3.z, wj[14], acc);
                    acc = fmaf(q3.w, wj[15], acc);
                    float m = fmaxf(acc + hs_cur[t], 0.0f) + EPS_GEN;
                    float ex = __expf(m);
                    se += ex;
                    sme += m * ex;
                }
            }
            if (!more) break;
            ((float4*)(myEA + (buf ^ 1) * 256))[lane] = st;
#pragma unroll
            for (int t = 0; t < 8; t++) hs_cur[t] = hs_next[t];
            c += 16;
            buf ^= 1;
        }
    }
    se += __shfl_xor(se, 32);
    sme += __shfl_xor(sme, 32);
    if (p == 0) {
        float r = (se > 0.0f) ? (sme / se) : 0.0f;
        conv[(size_t)v * H_DIM + j] = r + hv;
    }
}

// ---- K4: fused Lin (+folded-BN+ReLU on input, computed in-block from raw
// stats — replaces the k_bnfin launches) (+optional BN-stats output)
template <int IN_CH, bool BN_IN, bool STATS>
__global__ __launch_bounds__(256) void k_lin(
        const float* __restrict__ in, const float* __restrict__ w,
        const float* __restrict__ b, const float* __restrict__ stats_in,
        const float* __restrict__ g, const float* __restrict__ bb,
        float* __restrict__ out, float* __restrict__ stats_out) {
    __shared__ float sW[IN_CH * O_DIM];
    __shared__ float sB[O_DIM];
    __shared__ float sS[IN_CH], sH[IN_CH];
    __shared__ float sX[16 * IN_CH];
    __shared__ float r1[256], r2[256];
    int tid = threadIdx.x;
    for (int i = tid; i < IN_CH * O_DIM; i += 256) sW[i] = w[i];
    if (tid < O_DIM) sB[tid] = b[tid];
    if constexpr (BN_IN) {
        if (tid < IN_CH) {
            const float invN = 1.0f / (float)N_NODES;
            float mu = stats_in[tid] * invN;
            float var = fmaxf(stats_in[64 + tid] * invN - mu * mu, 0.0f);
            float rs = 1.0f / sqrtf(var + EPS_BN);
            float sc = g[tid] * rs;
            sS[tid] = sc;
            sH[tid] = bb[tid] - mu * sc;
        }
    }
    int ch = tid & 63, nl = tid >> 6;
    float s1 = 0.0f, s2 = 0.0f;
    const int ngroups = N_NODES / 16;  // 6250
    __syncthreads();
    for (int gq = blockIdx.x; gq < ngroups; gq += gridDim.x) {
        size_t base = (size_t)gq * 16 * IN_CH;
        __syncthreads();
        if constexpr (IN_CH == 64) {
            float4 v = ((const float4*)(in + base))[tid];
            if constexpr (BN_IN) {
                int c0 = (tid * 4) & 63;
                v.x = fmaxf(fmaf(v.x, sS[c0], sH[c0]), 0.0f);
                v.y = fmaxf(fmaf(v.y, sS[c0 + 1], sH[c0 + 1]), 0.0f);
                v.z = fmaxf(fmaf(v.z, sS[c0 + 2], sH[c0 + 2]), 0.0f);
                v.w = fmaxf(fmaf(v.w, sS[c0 + 3], sH[c0 + 3]), 0.0f);
            }
            ((float4*)sX)[tid] = v;
        } else {
            float2 v = ((const float2*)(in + base))[tid];
            if constexpr (BN_IN) {
                int c0 = (tid * 2) & (IN_CH - 1);
                v.x = fmaxf(fmaf(v.x, sS[c0], sH[c0]), 0.0f);
                v.y = fmaxf(fmaf(v.y, sS[c0 + 1], sH[c0 + 1]), 0.0f);
            }
            ((float2*)sX)[tid] = v;
        }
        __syncthreads();
#pragma unroll
        for (int q = 0; q < 4; q++) {
            const float* xr = &sX[(nl + 4 * q) * IN_CH];
            float acc = sB[ch];
#pragma unroll
            for (int k = 0; k < IN_CH; k++) acc = fmaf(xr[k], sW[k * O_DIM + ch], acc);
            out[(size_t)(gq * 16 + nl + 4 * q) * O_DIM + ch] = acc;
            if constexpr (STATS) { s1 += acc; s2 += acc * acc; }
        }
    }
    if constexpr (STATS) {
        __syncthreads();
        r1[tid] = s1; r2[tid] = s2;
        __syncthreads();
        if (tid < 64) {
            float a1 = r1[tid] + r1[tid + 64] + r1[tid + 128] + r1[tid + 192];
            float a2 = r2[tid] + r2[tid + 64] + r2[tid + 128] + r2[tid + 192];
            unsafeAtomicAdd(&stats_out[tid], a1);
            unsafeAtomicAdd(&stats_out[64 + tid], a2);
        }
    }
}

// ---- binary search helper: first index with batch[i] >= g
__device__ __forceinline__ int lb_batch(const int* __restrict__ batch, int g) {
    int lo = 0, hi = N_NODES;
    while (lo < hi) {
        int mid = (lo + hi) >> 1;
        if (batch[mid] < g) lo = mid + 1; else hi = mid;
    }
    return lo;
}

// ---- K7: segmented mean-pool partials (4 blocks per graph); bounds fused.
__global__ __launch_bounds__(256) void k_pool(
        const float* __restrict__ no, const int* __restrict__ batch,
        float* __restrict__ gsum) {
    int g = blockIdx.x >> 2, q = blockIdx.x & 3;
    __shared__ int sb[2];
    if (threadIdx.x == 0) sb[0] = lb_batch(batch, g);
    if (threadIdx.x == 1) sb[1] = lb_batch(batch, g + 1);
    __syncthreads();
    int s0 = sb[0], s1e = sb[1];
    int len = s1e - s0;
    int per = (len + 3) >> 2;
    int a = s0 + q * per;
    int bnd = min(s0 + (q + 1) * per, s1e);
    int ch = threadIdx.x & 63, nl = threadIdx.x >> 6;
    float acc = 0.0f;
    for (int n = a + nl; n < bnd; n += 4) acc += no[(size_t)n * O_DIM + ch];
    __shared__ float r[256];
    r[threadIdx.x] = acc;
    __syncthreads();
    if (threadIdx.x < 64) {
        float v = r[ch] + r[ch + 64] + r[ch + 128] + r[ch + 192];
        unsafeAtomicAdd(&gsum[g * O_DIM + ch], v);
    }
}

// ---- K8: head (one thread per graph); bounds fused.
__global__ void k_head(const float* __restrict__ gsum, const int* __restrict__ batch,
                       const float* __restrict__ action,
                       const float* __restrict__ pinw, const float* __restrict__ pinb,
                       const float* __restrict__ phw, const float* __restrict__ phb,
                       const float* __restrict__ pow_, const float* __restrict__ pob,
                       float* __restrict__ outp) {
    int g = threadIdx.x;
    if (g >= B_GRAPHS) return;
    int cnt = lb_batch(batch, g + 1) - lb_batch(batch, g);
    float inv = 1.0f / (float)max(cnt, 1);
    float mol[64];
#pragma unroll
    for (int c = 0; c < 64; c++) mol[c] = gsum[g * 64 + c] * inv;
    float fp[16];
#pragma unroll
    for (int j = 0; j < 16; j++) {
        float a = pinb[j];
        for (int c = 0; c < 64; c++) a = fmaf(mol[c], pinw[c * 16 + j], a);
        fp[j] = fmaxf(a, 0.0f);
    }
    float pol[10];
#pragma unroll
    for (int j = 0; j < 10; j++) {
        float a = phb[j];
        for (int k = 0; k < 16; k++) a = fmaf(fp[k], phw[k * 10 + j], a);
        for (int k = 0; k < 13; k++) a = fmaf(action[g * 13 + k], phw[(16 + k) * 10 + j], a);
        pol[j] = fmaxf(a, 0.0f);
    }
    float o = pob[0];
#pragma unroll
    for (int j = 0; j < 10; j++) o = fmaf(pol[j], pow_[j], o);
    outp[g] = o;
}

extern "C" void kernel_launch(void* const* d_in, const int* in_sizes, int n_in,
                              void* d_out, int out_size, void* d_ws, size_t ws_size,
                              hipStream_t stream) {
    const float* x      = (const float*)d_in[0];
    const int*   ei     = (const int*)d_in[1];
    const float* ea     = (const float*)d_in[2];
    const int*   batch  = (const int*)d_in[3];
    const float* action = (const float*)d_in[4];
    const float* node_w = (const float*)d_in[5];
    const float* node_b = (const float*)d_in[6];
    const float* edge_w = (const float*)d_in[7];
    const float* edge_b = (const float*)d_in[8];
    const float* w1 = (const float*)d_in[9];   const float* b1 = (const float*)d_in[10];
    const float* g1 = (const float*)d_in[11];  const float* bb1 = (const float*)d_in[12];
    const float* w2 = (const float*)d_in[13];  const float* b2 = (const float*)d_in[14];
    const float* g2 = (const float*)d_in[15];  const float* bb2 = (const float*)d_in[16];
    const float* w3 = (const float*)d_in[17];  const float* b3 = (const float*)d_in[18];
    const float* g3 = (const float*)d_in[19];  const float* bb3 = (const float*)d_in[20];
    const float* w4 = (const float*)d_in[21];  const float* b4 = (const float*)d_in[22];
    const float* pinw = (const float*)d_in[23]; const float* pinb = (const float*)d_in[24];
    const float* phw  = (const float*)d_in[25]; const float* phb  = (const float*)d_in[26];
    const float* pow_ = (const float*)d_in[27]; const float* pob  = (const float*)d_in[28];

    // ---- common workspace prefix
    char* wsb = (char*)d_ws;
    size_t off = 0;
    float* stats  = (float*)(wsb + off); off += 512 * 4;       // zeroed
    float* gsum   = (float*)(wsb + off); off += 4096 * 4;      // zeroed
    int*   offs   = (int*)  (wsb + off); off += 400128;        // deg->offs (zeroed)
    size_t zero_bytes = off;
    int*   cursor = (int*)  (wsb + off); off += 400128;
    int*   bsum   = (int*)  (wsb + off); off += 2048;
    int*   srcp   = (int*)  (wsb + off); off += (size_t)N_EDGES * 4;         // 12.8MB
    float* h      = (float*)(wsb + off); off += (size_t)N_NODES * H_DIM * 4; // 12.8MB
    float* conv   = (float*)(wsb + off); off += (size_t)N_NODES * H_DIM * 4; // 12.8MB
    size_t tail = off;
    // Path A: ea_perm (204.8MB) at tail; t1/t2 overlay it after gather.
    // Path B: sorted (25.6MB) at tail; t1 overlays sorted, t2 overlays h+conv.
    bool perm = (ws_size >= tail + (size_t)N_EDGES * E_INF * 4);
    float* eap    = (float*)(wsb + tail);
    uint2* sorted = (uint2*)(wsb + tail);
    float* t1, *t2;
    if (perm) {
        t1 = eap;                          // 25.6MB into ea_perm
        t2 = eap + (size_t)N_NODES * O_DIM;
    } else {
        t1 = (float*)sorted;               // 25.6MB overlay
        t2 = h;                            // 25.6MB spans h+conv
    }

    hipMemsetAsync(d_ws, 0, zero_bytes, stream);

    k_node_enc<<<N_NODES / 8, 256, 0, stream>>>(x, node_w, node_b, h);
    // build dst-CSR
    k_hist<<<(N_EDGES / 4 + 255) / 256, 256, 0, stream>>>(ei, offs);
    k_scan1<<<SCAN_BLOCKS, 256, 0, stream>>>(offs, cursor, bsum);
    k_scan3<<<SCAN_BLOCKS, 256, 0, stream>>>(offs, cursor, bsum);
    if (perm) {
        k_scatter_perm<<<(N_EDGES + 255) / 256, 256, 0, stream>>>(ei, cursor, ea, eap, srcp);
        k_gather<true><<<N_NODES / 4, 256, 0, stream>>>(eap, srcp, nullptr, offs,
                                                        edge_w, edge_b, h, conv);
    } else {
        k_scatter_idx<<<(N_EDGES + 255) / 256, 256, 0, stream>>>(ei, cursor, sorted);
        k_gather<false><<<N_NODES / 4, 256, 0, stream>>>(ea, nullptr, sorted, offs,
                                                         edge_w, edge_b, h, conv);
    }
    // MLP: P1 32->64 (stats1), P2/P3 64->64 (bn in, stats), P4 64->64 (bn in)
    k_lin<32, false, true><<<1250, 256, 0, stream>>>(conv, w1, b1, nullptr, nullptr, nullptr,
                                                     t1, stats + 0);
    k_lin<64, true, true><<<1250, 256, 0, stream>>>(t1, w2, b2, stats + 0, g1, bb1,
                                                    t2, stats + 128);
    k_lin<64, true, true><<<1250, 256, 0, stream>>>(t2, w3, b3, stats + 128, g2, bb2,
                                                    t1, stats + 256);
    k_lin<64, true, false><<<1250, 256, 0, stream>>>(t1, w4, b4, stats + 256, g3, bb3,
                                                     t2, nullptr);
    k_pool<<<B_GRAPHS * 4, 256, 0, stream>>>(t2, batch, gsum);
    k_head<<<1, 64, 0, stream>>>(gsum, batch, action, pinw, pinb, phw, phb, pow_, pob,
                                 (float*)d_out);
}

// Round 6
// 950.984 us; speedup vs baseline: 1.1633x; 1.0592x over previous
//
#include <hip/hip_runtime.h>
#include <cstdint>
#include <cstddef>

// CriticGNN: GENConv(softmax aggr) + MLP/BN + mean-pool + head. All fp32.
// R9 ledger audit: scatter 207 + gather ~150 + streaming estimates ~150
// leaves ~500us unaccounted -> the k_lin family. Its inner loop issued
// 2 scalar ds_read_b32 per FMA (x broadcast + weight) = 128 LDS instr/node
// on the single per-CU LDS pipe (~740cy/node -> ~120us/layer x4 + ~60
// node_enc). R10: weight column hoisted to VGPRs (wj[IN_CH], ch fixed per
// thread), x read as ds_read_b128 broadcasts (16 instr/node), BN fold
// vectorized float4, node_enc grid-stride. LDS instr/node: 128 -> ~17.

#define N_NODES 100000
#define N_EDGES 3200000
#define B_GRAPHS 64
#define F_INF 64
#define E_INF 16
#define A_DIM 13
#define H_DIM 32
#define O_DIM 64
#define EPS_GEN 1e-7f
#define EPS_BN 1e-5f
#define SCAN_BLOCKS 391

// ---- K1: node encoder h = x @ node_w + node_b  [N,64]x[64,32] -> [N,32]
// Grid-stride, 16 nodes/group; weight column in 64 VGPRs; b128 x reads.
__global__ __launch_bounds__(256) void k_node_enc(
        const float* __restrict__ x, const float* __restrict__ w,
        const float* __restrict__ b, float* __restrict__ h) {
    __shared__ float sX[16 * F_INF];
    int tid = threadIdx.x;
    int ch = tid & 31, nl = tid >> 5;    // 8 node-slots, 32 channels
    float wj[F_INF];
#pragma unroll
    for (int k = 0; k < F_INF; k++) wj[k] = w[k * H_DIM + ch];
    float bj = b[ch];
    const int ngroups = N_NODES / 16;    // 6250
    for (int gq = blockIdx.x; gq < ngroups; gq += gridDim.x) {
        size_t base = (size_t)gq * 16 * F_INF;
        __syncthreads();
        ((float4*)sX)[tid] = ((const float4*)(x + base))[tid];
        __syncthreads();
#pragma unroll
        for (int q = 0; q < 2; q++) {
            int node = q * 8 + nl;
            const float4* xr = (const float4*)&sX[node * F_INF];
            float acc = bj;
#pragma unroll
            for (int k4 = 0; k4 < 16; k4++) {
                float4 xv = xr[k4];
                acc = fmaf(xv.x, wj[4 * k4 + 0], acc);
                acc = fmaf(xv.y, wj[4 * k4 + 1], acc);
                acc = fmaf(xv.z, wj[4 * k4 + 2], acc);
                acc = fmaf(xv.w, wj[4 * k4 + 3], acc);
            }
            h[(size_t)(gq * 16 + node) * H_DIM + ch] = acc;
        }
    }
}

// ---- K2a: histogram of dst degrees (int4-vectorized reads)
__global__ __launch_bounds__(256) void k_hist(
        const int* __restrict__ ei, int* __restrict__ deg) {
    int i = blockIdx.x * 256 + threadIdx.x;
    if (i >= N_EDGES / 4) return;
    int4 d = ((const int4*)(ei + N_EDGES))[i];
    atomicAdd(&deg[d.x], 1);
    atomicAdd(&deg[d.y], 1);
    atomicAdd(&deg[d.z], 1);
    atomicAdd(&deg[d.w], 1);
}

// ---- K2b: per-256-block inclusive scan of deg -> incl, block sums -> bsum
__global__ __launch_bounds__(256) void k_scan1(
        const int* __restrict__ deg, int* __restrict__ incl,
        int* __restrict__ bsum) {
    __shared__ int s[256];
    int tid = threadIdx.x;
    int i = blockIdx.x * 256 + tid;
    int v = (i < N_NODES) ? deg[i] : 0;
    s[tid] = v;
    __syncthreads();
    for (int d = 1; d < 256; d <<= 1) {
        int t = (tid >= d) ? s[tid - d] : 0;
        __syncthreads();
        s[tid] += t;
        __syncthreads();
    }
    if (i < N_NODES) incl[i] = s[tid];
    if (tid == 255) bsum[blockIdx.x] = s[255];
}

// ---- K2d: finalize offsets + cursor copy; fuses the block-sum scan (scan2).
__global__ __launch_bounds__(256) void k_scan3(
        int* __restrict__ deg_offs, int* __restrict__ incl_cursor,
        const int* __restrict__ bsum) {
    __shared__ int red[256];
    int tid = threadIdx.x;
    int b = blockIdx.x;
    // exclusive prefix of bsum over blocks < b (<=2 strided loads/thread)
    int vsum = 0;
    for (int t = tid; t < b; t += 256) vsum += bsum[t];
    red[tid] = vsum;
    __syncthreads();
    for (int s = 128; s > 0; s >>= 1) {
        if (tid < s) red[tid] += red[tid + s];
        __syncthreads();
    }
    int prefix = red[0];
    int i = b * 256 + tid;
    if (i >= N_NODES) return;
    int o = prefix + incl_cursor[i] - deg_offs[i];  // exclusive prefix
    deg_offs[i] = o;
    incl_cursor[i] = o;
    if (i == 0) deg_offs[N_NODES] = N_EDGES;
}

// ---- K2e-A: scatter with ea permutation (streaming-gather path)
__global__ __launch_bounds__(256) void k_scatter_perm(
        const int* __restrict__ ei, int* __restrict__ cursor,
        const float* __restrict__ ea, float* __restrict__ eap,
        int* __restrict__ srcp) {
    int e = blockIdx.x * 256 + threadIdx.x;
    if (e >= N_EDGES) return;
    int src = ei[e];
    int d = ei[N_EDGES + e];
    const float4* er = (const float4*)(ea + (size_t)e * E_INF);
    float4 q0 = er[0], q1 = er[1], q2 = er[2], q3 = er[3];
    int pos = atomicAdd(&cursor[d], 1);
    float4* wr = (float4*)(eap + (size_t)pos * E_INF);
    wr[0] = q0; wr[1] = q1; wr[2] = q2; wr[3] = q3;
    srcp[pos] = src;
}

// ---- K2e-B: scatter edge records only (indexed-gather fallback)
__global__ __launch_bounds__(256) void k_scatter_idx(
        const int* __restrict__ ei, int* __restrict__ cursor,
        uint2* __restrict__ sorted) {
    int e = blockIdx.x * 256 + threadIdx.x;
    if (e >= N_EDGES) return;
    int src = ei[e];
    int d = ei[N_EDGES + e];
    int pos = atomicAdd(&cursor[d], 1);
    sorted[pos] = make_uint2((unsigned)e, (unsigned)src);
}

// ---- K3: atomic-free gather + softmax-aggregate + root-add.
// One wave per node; half-wave (32 lanes = 32 channels) per edge.
// 16-edge chunks, per-wave-private double-buffered LDS for ea rows:
//   stage chunk c+16 (1 coop wave load -> regs, ds_write after compute)
//   hs (h[src]) loads for chunk c+16 issued before computing chunk c
//   weight column in 16 VGPRs per lane; no barriers anywhere.
template <bool PERM>
__global__ __launch_bounds__(256, 4) void k_gather(
        const float* __restrict__ easrc, const int* __restrict__ srcp,
        const uint2* __restrict__ sorted, const int* __restrict__ offs,
        const float* __restrict__ ew, const float* __restrict__ eb,
        const float* __restrict__ h, float* __restrict__ conv) {
    __shared__ float sEA[4 * 2 * 256];   // 4 waves x 2 bufs x (16 edges x 16 f)
    int tid = threadIdx.x;
    int wave = tid >> 6, lane = tid & 63;
    int p = lane >> 5;     // half-wave id
    int j = lane & 31;     // channel
    int v = blockIdx.x * 4 + wave;       // grid 25000 -> exact cover
    int s0 = offs[v], s1 = offs[v + 1];
    float wj[16];
#pragma unroll
    for (int k = 0; k < 16; k++) wj[k] = ew[k * H_DIM + j];
    float bj = eb[j];
    float hv = h[(size_t)v * H_DIM + j];
    float se = 0.0f, sme = 0.0f;
    float* myEA = &sEA[wave * 512];

    if (s0 < s1) {
        const int s1m1 = s1 - 1;
        const int w16 = lane & 15;   // edge slot for src-chunk load
        const int row4 = lane >> 2;  // edge slot for ea staging (0..15)
        const int part = lane & 3;   // float4 part within ea row
        float hs_cur[8], hs_next[8];
        float4 st;
        uint2 srtN = make_uint2(0u, 0u);  // idx path: next-chunk (eid,src)
        unsigned scN = 0;                 // perm path: next-chunk src
        int c = s0, buf = 0;
        // ---- prologue: chunk0
        {
            unsigned sc0;
            if constexpr (PERM) {
                sc0 = (unsigned)srcp[min(c + w16, s1m1)];
                st = ((const float4*)easrc)[(size_t)min(c + row4, s1m1) * 4 + part];
            } else {
                uint2 srt0 = sorted[min(c + w16, s1m1)];
                sc0 = srt0.y;
                unsigned eid = (unsigned)__shfl((int)srt0.x, row4);
                st = ((const float4*)easrc)[(size_t)eid * 4 + part];
            }
#pragma unroll
            for (int t = 0; t < 8; t++) {
                int sc = __shfl((int)sc0, 2 * t + p);
                hs_cur[t] = h[(size_t)sc * H_DIM + j];
            }
            if constexpr (PERM) scN = (unsigned)srcp[min(c + 16 + w16, s1m1)];
            else srtN = sorted[min(c + 16 + w16, s1m1)];
            ((float4*)myEA)[lane] = st;   // buf0
        }
        for (;;) {
            bool more = (c + 16 < s1);
            if (more) {
                // stage chunk c+16 into regs; issue its hs loads; prefetch c+32 srcs
                if constexpr (PERM) {
                    st = ((const float4*)easrc)[(size_t)min(c + 16 + row4, s1m1) * 4 + part];
                } else {
                    unsigned eid = (unsigned)__shfl((int)srtN.x, row4);
                    st = ((const float4*)easrc)[(size_t)eid * 4 + part];
                }
                unsigned scsrc = PERM ? scN : srtN.y;
#pragma unroll
                for (int t = 0; t < 8; t++) {
                    int sc = __shfl((int)scsrc, 2 * t + p);
                    hs_next[t] = h[(size_t)sc * H_DIM + j];
                }
                if constexpr (PERM) scN = (unsigned)srcp[min(c + 32 + w16, s1m1)];
                else srtN = sorted[min(c + 32 + w16, s1m1)];
            }
            // compute chunk c from LDS[buf] + hs_cur
            const float* cb = &myEA[buf * 256];
#pragma unroll
            for (int t = 0; t < 8; t++) {
                int e = 2 * t + p;
                if (c + e < s1) {
                    const float4* er = (const float4*)&cb[e * 16];
                    float4 q0 = er[0], q1 = er[1], q2 = er[2], q3 = er[3];
                    float acc = bj;
                    acc = fmaf(q0.x, wj[0], acc);
                    acc = fmaf(q0.y, wj[1], acc);
                    acc = fmaf(q0.z, wj[2], acc);
                    acc = fmaf(q0.w, wj[3], acc);
                    acc = fmaf(q1.x, wj[4], acc);
                    acc = fmaf(q1.y, wj[5], acc);
                    acc = fmaf(q1.z, wj[6], acc);
                    acc = fmaf(q1.w, wj[7], acc);
                    acc = fmaf(q2.x, wj[8], acc);
                    acc = fmaf(q2.y, wj[9], acc);
                    acc = fmaf(q2.z, wj[10], acc);
                    acc = fmaf(q2.w, wj[11], acc);
                    acc = fmaf(q3.x, wj[12], acc);
                    acc = fmaf(q3.y, wj[13], acc);
                    acc = fmaf(q3.z, wj[14], acc);
                    acc = fmaf(q3.w, wj[15], acc);
                    float m = fmaxf(acc + hs_cur[t], 0.0f) + EPS_GEN;
                    float ex = __expf(m);
                    se += ex;
                    sme += m * ex;
                }
            }
            if (!more) break;
            ((float4*)(myEA + (buf ^ 1) * 256))[lane] = st;
#pragma unroll
            for (int t = 0; t < 8; t++) hs_cur[t] = hs_next[t];
            c += 16;
            buf ^= 1;
        }
    }
    se += __shfl_xor(se, 32);
    sme += __shfl_xor(sme, 32);
    if (p == 0) {
        float r = (se > 0.0f) ? (sme / se) : 0.0f;
        conv[(size_t)v * H_DIM + j] = r + hv;
    }
}

// ---- K4: fused Lin (+folded-BN+ReLU on input from raw stats) (+BN-stats out)
// Weight column in VGPRs (ch fixed/thread); x via ds_read_b128 broadcasts.
template <int IN_CH, bool BN_IN, bool STATS>
__global__ __launch_bounds__(256) void k_lin(
        const float* __restrict__ in, const float* __restrict__ w,
        const float* __restrict__ b, const float* __restrict__ stats_in,
        const float* __restrict__ g, const float* __restrict__ bb,
        float* __restrict__ out, float* __restrict__ stats_out) {
    __shared__ float sS[IN_CH], sH[IN_CH];
    __shared__ float sX[16 * IN_CH];
    __shared__ float r1[256], r2[256];
    int tid = threadIdx.x;
    int ch = tid & 63, nl = tid >> 6;
    float wj[IN_CH];
#pragma unroll
    for (int k = 0; k < IN_CH; k++) wj[k] = w[k * O_DIM + ch];
    float bj = b[ch];
    if constexpr (BN_IN) {
        if (tid < IN_CH) {
            const float invN = 1.0f / (float)N_NODES;
            float mu = stats_in[tid] * invN;
            float var = fmaxf(stats_in[64 + tid] * invN - mu * mu, 0.0f);
            float rs = 1.0f / sqrtf(var + EPS_BN);
            float sc = g[tid] * rs;
            sS[tid] = sc;
            sH[tid] = bb[tid] - mu * sc;
        }
    }
    float s1 = 0.0f, s2 = 0.0f;
    const int ngroups = N_NODES / 16;  // 6250
    __syncthreads();
    for (int gq = blockIdx.x; gq < ngroups; gq += gridDim.x) {
        size_t base = (size_t)gq * 16 * IN_CH;
        __syncthreads();
        if constexpr (IN_CH == 64) {
            float4 v = ((const float4*)(in + base))[tid];
            if constexpr (BN_IN) {
                float4 sv = ((const float4*)sS)[tid & 15];
                float4 hv = ((const float4*)sH)[tid & 15];
                v.x = fmaxf(fmaf(v.x, sv.x, hv.x), 0.0f);
                v.y = fmaxf(fmaf(v.y, sv.y, hv.y), 0.0f);
                v.z = fmaxf(fmaf(v.z, sv.z, hv.z), 0.0f);
                v.w = fmaxf(fmaf(v.w, sv.w, hv.w), 0.0f);
            }
            ((float4*)sX)[tid] = v;
        } else {
            float2 v = ((const float2*)(in + base))[tid];
            if constexpr (BN_IN) {
                int c0 = (tid * 2) & (IN_CH - 1);
                v.x = fmaxf(fmaf(v.x, sS[c0], sH[c0]), 0.0f);
                v.y = fmaxf(fmaf(v.y, sS[c0 + 1], sH[c0 + 1]), 0.0f);
            }
            ((float2*)sX)[tid] = v;
        }
        __syncthreads();
#pragma unroll
        for (int q = 0; q < 4; q++) {
            const float4* xr = (const float4*)&sX[(nl + 4 * q) * IN_CH];
            float acc = bj;
#pragma unroll
            for (int k4 = 0; k4 < IN_CH / 4; k4++) {
                float4 xv = xr[k4];
                acc = fmaf(xv.x, wj[4 * k4 + 0], acc);
                acc = fmaf(xv.y, wj[4 * k4 + 1], acc);
                acc = fmaf(xv.z, wj[4 * k4 + 2], acc);
                acc = fmaf(xv.w, wj[4 * k4 + 3], acc);
            }
            out[(size_t)(gq * 16 + nl + 4 * q) * O_DIM + ch] = acc;
            if constexpr (STATS) { s1 += acc; s2 += acc * acc; }
        }
    }
    if constexpr (STATS) {
        __syncthreads();
        r1[tid] = s1; r2[tid] = s2;
        __syncthreads();
        if (tid < 64) {
            float a1 = r1[tid] + r1[tid + 64] + r1[tid + 128] + r1[tid + 192];
            float a2 = r2[tid] + r2[tid + 64] + r2[tid + 128] + r2[tid + 192];
            unsafeAtomicAdd(&stats_out[tid], a1);
            unsafeAtomicAdd(&stats_out[64 + tid], a2);
        }
    }
}

// ---- binary search helper: first index with batch[i] >= g
__device__ __forceinline__ int lb_batch(const int* __restrict__ batch, int g) {
    int lo = 0, hi = N_NODES;
    while (lo < hi) {
        int mid = (lo + hi) >> 1;
        if (batch[mid] < g) lo = mid + 1; else hi = mid;
    }
    return lo;
}

// ---- K7: segmented mean-pool partials (4 blocks per graph); bounds fused.
__global__ __launch_bounds__(256) void k_pool(
        const float* __restrict__ no, const int* __restrict__ batch,
        float* __restrict__ gsum) {
    int g = blockIdx.x >> 2, q = blockIdx.x & 3;
    __shared__ int sb[2];
    if (threadIdx.x == 0) sb[0] = lb_batch(batch, g);
    if (threadIdx.x == 1) sb[1] = lb_batch(batch, g + 1);
    __syncthreads();
    int s0 = sb[0], s1e = sb[1];
    int len = s1e - s0;
    int per = (len + 3) >> 2;
    int a = s0 + q * per;
    int bnd = min(s0 + (q + 1) * per, s1e);
    int ch = threadIdx.x & 63, nl = threadIdx.x >> 6;
    float acc = 0.0f;
    for (int n = a + nl; n < bnd; n += 4) acc += no[(size_t)n * O_DIM + ch];
    __shared__ float r[256];
    r[threadIdx.x] = acc;
    __syncthreads();
    if (threadIdx.x < 64) {
        float v = r[ch] + r[ch + 64] + r[ch + 128] + r[ch + 192];
        unsafeAtomicAdd(&gsum[g * O_DIM + ch], v);
    }
}

// ---- K8: head (one thread per graph); bounds fused.
__global__ void k_head(const float* __restrict__ gsum, const int* __restrict__ batch,
                       const float* __restrict__ action,
                       const float* __restrict__ pinw, const float* __restrict__ pinb,
                       const float* __restrict__ phw, const float* __restrict__ phb,
                       const float* __restrict__ pow_, const float* __restrict__ pob,
                       float* __restrict__ outp) {
    int g = threadIdx.x;
    if (g >= B_GRAPHS) return;
    int cnt = lb_batch(batch, g + 1) - lb_batch(batch, g);
    float inv = 1.0f / (float)max(cnt, 1);
    float mol[64];
#pragma unroll
    for (int c = 0; c < 64; c++) mol[c] = gsum[g * 64 + c] * inv;
    float fp[16];
#pragma unroll
    for (int j = 0; j < 16; j++) {
        float a = pinb[j];
        for (int c = 0; c < 64; c++) a = fmaf(mol[c], pinw[c * 16 + j], a);
        fp[j] = fmaxf(a, 0.0f);
    }
    float pol[10];
#pragma unroll
    for (int j = 0; j < 10; j++) {
        float a = phb[j];
        for (int k = 0; k < 16; k++) a = fmaf(fp[k], phw[k * 10 + j], a);
        for (int k = 0; k < 13; k++) a = fmaf(action[g * 13 + k], phw[(16 + k) * 10 + j], a);
        pol[j] = fmaxf(a, 0.0f);
    }
    float o = pob[0];
#pragma unroll
    for (int j = 0; j < 10; j++) o = fmaf(pol[j], pow_[j], o);
    outp[g] = o;
}

extern "C" void kernel_launch(void* const* d_in, const int* in_sizes, int n_in,
                              void* d_out, int out_size, void* d_ws, size_t ws_size,
                              hipStream_t stream) {
    const float* x      = (const float*)d_in[0];
    const int*   ei     = (const int*)d_in[1];
    const float* ea     = (const float*)d_in[2];
    const int*   batch  = (const int*)d_in[3];
    const float* action = (const float*)d_in[4];
    const float* node_w = (const float*)d_in[5];
    const float* node_b = (const float*)d_in[6];
    const float* edge_w = (const float*)d_in[7];
    const float* edge_b = (const float*)d_in[8];
    const float* w1 = (const float*)d_in[9];   const float* b1 = (const float*)d_in[10];
    const float* g1 = (const float*)d_in[11];  const float* bb1 = (const float*)d_in[12];
    const float* w2 = (const float*)d_in[13];  const float* b2 = (const float*)d_in[14];
    const float* g2 = (const float*)d_in[15];  const float* bb2 = (const float*)d_in[16];
    const float* w3 = (const float*)d_in[17];  const float* b3 = (const float*)d_in[18];
    const float* g3 = (const float*)d_in[19];  const float* bb3 = (const float*)d_in[20];
    const float* w4 = (const float*)d_in[21];  const float* b4 = (const float*)d_in[22];
    const float* pinw = (const float*)d_in[23]; const float* pinb = (const float*)d_in[24];
    const float* phw  = (const float*)d_in[25]; const float* phb  = (const float*)d_in[26];
    const float* pow_ = (const float*)d_in[27]; const float* pob  = (const float*)d_in[28];

    // ---- common workspace prefix
    char* wsb = (char*)d_ws;
    size_t off = 0;
    float* stats  = (float*)(wsb + off); off += 512 * 4;       // zeroed
    float* gsum   = (float*)(wsb + off); off += 4096 * 4;      // zeroed
    int*   offs   = (int*)  (wsb + off); off += 400128;        // deg->offs (zeroed)
    size_t zero_bytes = off;
    int*   cursor = (int*)  (wsb + off); off += 400128;
    int*   bsum   = (int*)  (wsb + off); off += 2048;
    int*   srcp   = (int*)  (wsb + off); off += (size_t)N_EDGES * 4;         // 12.8MB
    float* h      = (float*)(wsb + off); off += (size_t)N_NODES * H_DIM * 4; // 12.8MB
    float* conv   = (float*)(wsb + off); off += (size_t)N_NODES * H_DIM * 4; // 12.8MB
    size_t tail = off;
    // Path A: ea_perm (204.8MB) at tail; t1/t2 overlay it after gather.
    // Path B: sorted (25.6MB) at tail; t1 overlays sorted, t2 overlays h+conv.
    bool perm = (ws_size >= tail + (size_t)N_EDGES * E_INF * 4);
    float* eap    = (float*)(wsb + tail);
    uint2* sorted = (uint2*)(wsb + tail);
    float* t1, *t2;
    if (perm) {
        t1 = eap;                          // 25.6MB into ea_perm
        t2 = eap + (size_t)N_NODES * O_DIM;
    } else {
        t1 = (float*)sorted;               // 25.6MB overlay
        t2 = h;                            // 25.6MB spans h+conv
    }

    hipMemsetAsync(d_ws, 0, zero_bytes, stream);

    k_node_enc<<<1250, 256, 0, stream>>>(x, node_w, node_b, h);
    // build dst-CSR
    k_hist<<<(N_EDGES / 4 + 255) / 256, 256, 0, stream>>>(ei, offs);
    k_scan1<<<SCAN_BLOCKS, 256, 0, stream>>>(offs, cursor, bsum);
    k_scan3<<<SCAN_BLOCKS, 256, 0, stream>>>(offs, cursor, bsum);
    if (perm) {
        k_scatter_perm<<<(N_EDGES + 255) / 256, 256, 0, stream>>>(ei, cursor, ea, eap, srcp);
        k_gather<true><<<N_NODES / 4, 256, 0, stream>>>(eap, srcp, nullptr, offs,
                                                        edge_w, edge_b, h, conv);
    } else {
        k_scatter_idx<<<(N_EDGES + 255) / 256, 256, 0, stream>>>(ei, cursor, sorted);
        k_gather<false><<<N_NODES / 4, 256, 0, stream>>>(ea, nullptr, sorted, offs,
                                                         edge_w, edge_b, h, conv);
    }
    // MLP: P1 32->64 (stats1), P2/P3 64->64 (bn in, stats), P4 64->64 (bn in)
    k_lin<32, false, true><<<1250, 256, 0, stream>>>(conv, w1, b1, nullptr, nullptr, nullptr,
                                                     t1, stats + 0);
    k_lin<64, true, true><<<1250, 256, 0, stream>>>(t1, w2, b2, stats + 0, g1, bb1,
                                                    t2, stats + 128);
    k_lin<64, true, true><<<1250, 256, 0, stream>>>(t2, w3, b3, stats + 128, g2, bb2,
                                                    t1, stats + 256);
    k_lin<64, true, false><<<1250, 256, 0, stream>>>(t1, w4, b4, stats + 256, g3, bb3,
                                                     t2, nullptr);
    k_pool<<<B_GRAPHS * 4, 256, 0, stream>>>(t2, batch, gsum);
    k_head<<<1, 64, 0, stream>>>(gsum, batch, action, pinw, pinb, phw, phb, pow_, pob,
                                 (float*)d_out);
}